// Round 1
// baseline (460.439 us; speedup 1.0000x reference)
//
#include <hip/hip_runtime.h>
#include <cstdint>
#include <cstddef>

// Problem dims (fixed by the reference: B=8, S=2048, DIN=1152, DOUT=4608)
#define M_DIM 16384   // B*S
#define N_DIM 4608    // DOUT
#define K_DIM 1152    // DIN
#define NKT   (K_DIM / 128)   // 9 K-tiles of 128 int8 bytes

typedef __attribute__((ext_vector_type(8))) __bf16 bf16x8;
typedef __attribute__((ext_vector_type(4))) float  f32x4;
typedef __attribute__((ext_vector_type(4))) int    v4i;

__device__ __forceinline__ unsigned short f2bf(float f) {
    unsigned int u = __float_as_uint(f);
    unsigned int r = (u + 0x7FFFu + ((u >> 16) & 1u)) >> 16;
    return (unsigned short)r;
}

__device__ __forceinline__ float gelu_tanh_f(float v) {
    // 0.5*v*(1+tanh(c0*(v + c1*v^3))), stable tanh via exp(-2|u|)
    float u = 0.7978845608028654f * (v + 0.044715f * v * v * v);
    float a = fabsf(u);
    float t = __expf(-2.0f * a);
    float th = (1.0f - t) / (1.0f + t);
    th = (u < 0.0f) ? -th : th;
    return 0.5f * v * (1.0f + th);
}

// ---------------- merged prepass ----------------
// Blocks [0, M_DIM/4): per-row dynamic int8 quantization of A (1 wave/row).
// Blocks [M_DIM/4, ...): pack int32 weights -> int8 (exact).
#define QA_BLOCKS (M_DIM / 4)
#define W4_COUNT  ((N_DIM * K_DIM) / 4)
#define PW_BLOCKS ((W4_COUNT + 255) / 256)

__global__ void prepass(const float* __restrict__ A,
                        const int* __restrict__ w,
                        signed char* __restrict__ qa,
                        float* __restrict__ sA,
                        signed char* __restrict__ qw) {
    if (blockIdx.x < QA_BLOCKS) {
        const int lane = threadIdx.x & 63;
        const int row  = blockIdx.x * 4 + (threadIdx.x >> 6);
        const float2* src = (const float2*)(A + (size_t)row * K_DIM);
        float2 v[9];
        float amax = 0.f;
#pragma unroll
        for (int j = 0; j < 9; ++j) {
            v[j] = src[j * 64 + lane];
            amax = fmaxf(amax, fmaxf(fabsf(v[j].x), fabsf(v[j].y)));
        }
#pragma unroll
        for (int off = 32; off > 0; off >>= 1)
            amax = fmaxf(amax, __shfl_xor(amax, off));
        amax = fmaxf(amax, 1e-30f);
        float inv = 127.0f / amax;
        if (lane == 0) sA[row] = amax * (1.0f / 127.0f);
        char2* dst = (char2*)(qa + (size_t)row * K_DIM);
#pragma unroll
        for (int j = 0; j < 9; ++j) {
            char2 o;
            o.x = (signed char)__float2int_rn(v[j].x * inv);
            o.y = (signed char)__float2int_rn(v[j].y * inv);
            dst[j * 64 + lane] = o;
        }
    } else {
        int i = (blockIdx.x - QA_BLOCKS) * 256 + threadIdx.x;
        if (i >= W4_COUNT) return;
        int4 v = ((const int4*)w)[i];
        char4 o;
        o.x = (signed char)v.x; o.y = (signed char)v.y;
        o.z = (signed char)v.z; o.w = (signed char)v.w;
        ((char4*)qw)[i] = o;
    }
}

// ---------------- i8 GEMM, 256x256 tile, 8-phase counted-vmcnt schedule ----
// 512 threads = 8 waves (2M x 4N), per-wave 128x64 output, BK=128 int8.
// LDS: 2 dbuf x (A 32KB + B 32KB) = 128 KiB. Rows are 128 B = 8 x 16B chunks
// with XOR swizzle chunk ^= (row&7): linear gload_lds dest + pre-swizzled
// global source + swizzled ds_read (both-sides rule).
// Per K-tile: 4 phases, each = {ds_read subtile; issue 1 half-tile prefetch;
// s_barrier; MFMA quadrant (16x mfma_i32_16x16x64_i8, setprio-wrapped);
// s_barrier}. Counted vmcnt(4) ONCE per K-tile (never 0 in steady state).
// Region free-phase proof: B-halves of live buffer free after P2, A-halves
// after P3 => issue order A0(kt+1)@P1, A1(kt+1)@P2, B0(kt+2)@P3, B1(kt+2)@P4.

template <int MH, int NH>
__device__ __forceinline__ void mfma_quad(v4i (&acc)[2][4][2][2],
                                          v4i (&a)[4][2],
                                          v4i (&b)[2][2][2]) {
    __builtin_amdgcn_s_setprio(1);
#pragma unroll
    for (int s = 0; s < 2; ++s)
#pragma unroll
        for (int mt = 0; mt < 4; ++mt)
#pragma unroll
            for (int nt = 0; nt < 2; ++nt)
                acc[MH][mt][NH][nt] = __builtin_amdgcn_mfma_i32_16x16x64_i8(
                    a[mt][s], b[NH][nt][s], acc[MH][mt][NH][nt], 0, 0, 0);
    __builtin_amdgcn_s_setprio(0);
}

__global__ __launch_bounds__(512, 2) void qgemm_i8_8phase(
    const signed char* __restrict__ Aq,
    const signed char* __restrict__ Wq,
    const float* __restrict__ sA,
    const float* __restrict__ w_scale,
    const float* __restrict__ bias,
    float* __restrict__ out) {
    // [buf][mat(A/B)][row*128 + slot*16 + byte]
    __shared__ __align__(16) signed char lds[2][2][256 * 128];

    const int tid    = threadIdx.x;
    const int l      = tid & 63;
    const int wv     = tid >> 6;       // 0..7
    const int lane16 = l & 15;
    const int quad   = l >> 4;

    // XCD-aware bijective swizzle: 1152 blocks = 8 XCDs x 144.
    // Within an XCD chunk, n-tile varies fastest -> A-panel (2.4 MB) is
    // L2-resident per XCD.
    const int bid = blockIdx.x;
    const int swz = (bid & 7) * (1152 / 8) + (bid >> 3);
    const int mt0 = (swz / 18) * 256;
    const int nt0 = (swz % 18) * 256;

    const int wm = (wv & 1) * 128;
    const int wn = (wv >> 1) * 64;

    // stage one 16KB half-tile (128 rows x 128B) = 2 x global_load_lds/thread
    auto stage_half = [&](int buf, int mat, int half, int kt) {
        const signed char* gbase =
            (mat == 0) ? (Aq + (size_t)mt0 * K_DIM) : (Wq + (size_t)nt0 * K_DIM);
#pragma unroll
        for (int j = 0; j < 2; ++j) {
            int q   = j * 512 + tid;            // 16B-chunk idx in half-tile
            int row = half * 128 + (q >> 3);    // tile row 0..255
            int c   = (q & 7) ^ (row & 7);      // pre-swizzled global chunk
            const signed char* g = gbase + (size_t)row * K_DIM + kt * 128 + c * 16;
            signed char* d = &lds[buf][mat][half * 16384 + (j * 512 + wv * 64) * 16];
            __builtin_amdgcn_global_load_lds(
                (const __attribute__((address_space(1))) unsigned int*)g,
                (__attribute__((address_space(3))) unsigned int*)d, 16, 0, 0);
        }
    };

    v4i acc[2][4][2][2];
#pragma unroll
    for (int mh = 0; mh < 2; ++mh)
#pragma unroll
        for (int mt = 0; mt < 4; ++mt)
#pragma unroll
            for (int nh = 0; nh < 2; ++nh)
#pragma unroll
                for (int nt = 0; nt < 2; ++nt)
                    acc[mh][mt][nh][nt] = v4i{0, 0, 0, 0};

    v4i a[4][2];      // current-mh A frags
    v4i b[2][2][2];   // both-nh B frags (live across the K-tile)

    auto ldA = [&](int cur, int mh, int mt, int s) -> v4i {
        int r = wm + mh * 64 + mt * 16 + lane16;
        int p = (s * 4 + quad) ^ (r & 7);
        return *(const v4i*)&lds[cur][0][r * 128 + p * 16];
    };
    auto ldB = [&](int cur, int nh, int nt, int s) -> v4i {
        int r = wn + nh * 32 + nt * 16 + lane16;
        int p = (s * 4 + quad) ^ (r & 7);
        return *(const v4i*)&lds[cur][1][r * 128 + p * 16];
    };

    // -------- prologue: kt0 fully + kt1 B-halves (12 loads/thread) --------
    stage_half(0, 0, 0, 0); stage_half(0, 0, 1, 0);
    stage_half(0, 1, 0, 0); stage_half(0, 1, 1, 0);
    stage_half(1, 1, 0, 1); stage_half(1, 1, 1, 1);
    asm volatile("s_waitcnt vmcnt(4)" ::: "memory");  // kt0 done, B(kt1) flying
    __builtin_amdgcn_sched_barrier(0);
    __builtin_amdgcn_s_barrier();

    for (int kt = 0; kt < NKT; ++kt) {
        const int cur = kt & 1, nxt = cur ^ 1;
        // ---- P1: quad (0,0) — 12 ds_reads; prefetch A0(kt+1)
#pragma unroll
        for (int mt = 0; mt < 4; ++mt)
#pragma unroll
            for (int s = 0; s < 2; ++s) a[mt][s] = ldA(cur, 0, mt, s);
#pragma unroll
        for (int nt = 0; nt < 2; ++nt)
#pragma unroll
            for (int s = 0; s < 2; ++s) b[0][nt][s] = ldB(cur, 0, nt, s);
        if (kt + 1 < NKT) stage_half(nxt, 0, 0, kt + 1);
        __builtin_amdgcn_s_barrier();
        mfma_quad<0, 0>(acc, a, b);
        __builtin_amdgcn_s_barrier();
        // ---- P2: quad (0,1) — 4 ds_reads; prefetch A1(kt+1)
#pragma unroll
        for (int nt = 0; nt < 2; ++nt)
#pragma unroll
            for (int s = 0; s < 2; ++s) b[1][nt][s] = ldB(cur, 1, nt, s);
        if (kt + 1 < NKT) stage_half(nxt, 0, 1, kt + 1);
        __builtin_amdgcn_s_barrier();
        mfma_quad<0, 1>(acc, a, b);
        __builtin_amdgcn_s_barrier();
        // ---- P3: quad (1,1) — 8 ds_reads; prefetch B0(kt+2) into cur
        //      (B-halves of cur are free after P2-end barrier)
#pragma unroll
        for (int mt = 0; mt < 4; ++mt)
#pragma unroll
            for (int s = 0; s < 2; ++s) a[mt][s] = ldA(cur, 1, mt, s);
        if (kt + 2 < NKT) stage_half(cur, 1, 0, kt + 2);
        __builtin_amdgcn_s_barrier();
        mfma_quad<1, 1>(acc, a, b);
        __builtin_amdgcn_s_barrier();
        // ---- P4: quad (1,0) — 0 ds_reads; prefetch B1(kt+2); boundary wait
        if (kt + 2 < NKT) stage_half(cur, 1, 1, kt + 2);
        mfma_quad<1, 0>(acc, a, b);
        if (kt + 2 < NKT) {
            asm volatile("s_waitcnt vmcnt(4)" ::: "memory");  // kt+1 complete
        } else if (kt + 1 < NKT) {
            asm volatile("s_waitcnt vmcnt(0)" ::: "memory");  // tail drain
        }
        __builtin_amdgcn_sched_barrier(0);
        __builtin_amdgcn_s_barrier();
    }

    // epilogue: v = sA[m] * acc * w_scale[n] + bias[n] -> gelu -> nt store
    // C/D layout (m89/m91, dtype-independent): col=lane&15, row=quad*4+reg
#pragma unroll
    for (int nh = 0; nh < 2; ++nh)
#pragma unroll
        for (int nt = 0; nt < 2; ++nt) {
            int n    = nt0 + wn + nh * 32 + nt * 16 + lane16;
            float sc = w_scale[n];
            float bi = bias[n];
#pragma unroll
            for (int mh = 0; mh < 2; ++mh)
#pragma unroll
                for (int mt = 0; mt < 4; ++mt) {
                    int mbase = mt0 + wm + mh * 64 + mt * 16 + quad * 4;
#pragma unroll
                    for (int r = 0; r < 4; ++r) {
                        float v = (float)acc[mh][mt][nh][nt][r] * sA[mbase + r] * sc + bi;
                        __builtin_nontemporal_store(
                            gelu_tanh_f(v), &out[(size_t)(mbase + r) * N_DIM + n]);
                    }
                }
        }
}

// ---------------- bf16 fused fallback (if ws too small) --------------------
__global__ void qgelu_gemm_bf16_fused(const float* __restrict__ Af,
                                      const int* __restrict__ Wi,
                                      const float* __restrict__ w_scale,
                                      const float* __restrict__ bias,
                                      float* __restrict__ out) {
    __shared__ __align__(16) unsigned short As[128 * 64];
    __shared__ __align__(16) unsigned short Bs[128 * 64];

    const int tid    = threadIdx.x;
    const int l      = tid & 63;
    const int wv     = tid >> 6;
    const int lane16 = l & 15;
    const int quad   = l >> 4;
    const int m0 = blockIdx.x * 128;
    const int n0 = blockIdx.y * 128;
    const int wm = (wv & 1) * 64;
    const int wn = (wv >> 1) * 64;

    f32x4 acc[4][4];
#pragma unroll
    for (int i = 0; i < 4; ++i)
#pragma unroll
        for (int j = 0; j < 4; ++j) acc[i][j] = f32x4{0.f, 0.f, 0.f, 0.f};

    for (int kt = 0; kt < K_DIM / 64; ++kt) {
        __syncthreads();
#pragma unroll
        for (int i = 0; i < 8; ++i) {
            int g    = i * 256 + tid;
            int row  = g >> 4;
            int grp  = g & 15;
            int c    = grp >> 1;
            int half = g & 1;
            int p    = c ^ (row & 7);
            int off  = row * 64 + p * 8 + half * 4;
            {
                float4 v = *(const float4*)(Af + (size_t)(m0 + row) * K_DIM + kt * 64 + grp * 4);
                ushort4 o;
                o.x = f2bf(v.x); o.y = f2bf(v.y); o.z = f2bf(v.z); o.w = f2bf(v.w);
                *(ushort4*)(As + off) = o;
            }
            {
                int4 v = *(const int4*)(Wi + (size_t)(n0 + row) * K_DIM + kt * 64 + grp * 4);
                ushort4 o;
                o.x = f2bf((float)v.x); o.y = f2bf((float)v.y);
                o.z = f2bf((float)v.z); o.w = f2bf((float)v.w);
                *(ushort4*)(Bs + off) = o;
            }
        }
        __syncthreads();

#pragma unroll
        for (int s = 0; s < 2; ++s) {
            bf16x8 af[4], bfr[4];
#pragma unroll
            for (int mt = 0; mt < 4; ++mt) {
                int row = wm + mt * 16 + lane16;
                int p   = (s * 4 + quad) ^ (row & 7);
                af[mt]  = *(const bf16x8*)(As + row * 64 + p * 8);
            }
#pragma unroll
            for (int nt = 0; nt < 4; ++nt) {
                int row = wn + nt * 16 + lane16;
                int p   = (s * 4 + quad) ^ (row & 7);
                bfr[nt] = *(const bf16x8*)(Bs + row * 64 + p * 8);
            }
#pragma unroll
            for (int mt = 0; mt < 4; ++mt)
#pragma unroll
                for (int nt = 0; nt < 4; ++nt)
                    acc[mt][nt] = __builtin_amdgcn_mfma_f32_16x16x32_bf16(
                        af[mt], bfr[nt], acc[mt][nt], 0, 0, 0);
        }
    }

#pragma unroll
    for (int nt = 0; nt < 4; ++nt) {
        int n    = n0 + wn + nt * 16 + lane16;
        float sc = w_scale[n];
        float bi = bias[n];
#pragma unroll
        for (int mt = 0; mt < 4; ++mt) {
#pragma unroll
            for (int r = 0; r < 4; ++r) {
                int m   = m0 + wm + mt * 16 + quad * 4 + r;
                float v = acc[mt][nt][r] * sc + bi;
                __builtin_nontemporal_store(
                    gelu_tanh_f(v), &out[(size_t)m * N_DIM + n]);
            }
        }
    }
}

extern "C" void kernel_launch(void* const* d_in, const int* in_sizes, int n_in,
                              void* d_out, int out_size, void* d_ws, size_t ws_size,
                              hipStream_t stream) {
    const float* hs   = (const float*)d_in[0];  // [8,2048,1152] fp32
    const int*   w8   = (const int*)d_in[1];    // [4608,1152] int32 (int8 values)
    const float* wsc  = (const float*)d_in[2];  // [4608]
    const float* bias = (const float*)d_in[3];  // [4608]
    float* out = (float*)d_out;                 // [8,2048,4608] fp32

    const size_t nA = (size_t)M_DIM * K_DIM;  // int8 elems
    const size_t nW = (size_t)N_DIM * K_DIM;
    const size_t need = nA + nW + (size_t)M_DIM * sizeof(float);

    if (ws_size >= need) {
        signed char* qa = (signed char*)d_ws;
        signed char* qw = qa + nA;
        float* sA = (float*)(qa + nA + nW);  // 16B-aligned (nA+nW % 16 == 0)
        prepass<<<QA_BLOCKS + PW_BLOCKS, 256, 0, stream>>>(hs, w8, qa, sA, qw);
        qgemm_i8_8phase<<<dim3((M_DIM / 256) * (N_DIM / 256)), 512, 0, stream>>>(
            qa, qw, sA, wsc, bias, out);
    } else {
        dim3 grid(M_DIM / 128, N_DIM / 128);
        qgelu_gemm_bf16_fused<<<grid, 256, 0, stream>>>(hs, w8, wsc, bias, out);
    }
}

// Round 4
// 444.118 us; speedup vs baseline: 1.0367x; 1.0367x over previous
//
#include <hip/hip_runtime.h>
#include <cstdint>
#include <cstddef>

// Problem dims (fixed by the reference: B=8, S=2048, DIN=1152, DOUT=4608)
#define M_DIM 16384   // B*S
#define N_DIM 4608    // DOUT
#define K_DIM 1152    // DIN
#define NKT   (K_DIM / 128)   // 9 K-tiles of 128 int8 bytes

typedef __attribute__((ext_vector_type(8))) __bf16 bf16x8;
typedef __attribute__((ext_vector_type(4))) float  f32x4;
typedef __attribute__((ext_vector_type(4))) int    v4i;

__device__ __forceinline__ unsigned short f2bf(float f) {
    unsigned int u = __float_as_uint(f);
    unsigned int r = (u + 0x7FFFu + ((u >> 16) & 1u)) >> 16;
    return (unsigned short)r;
}

__device__ __forceinline__ float gelu_tanh_f(float v) {
    // 0.5*v*(1+tanh(u)) == v * sigmoid(2u), u = c0*(v + c1*v^3)
    // 2u = v*(2*c0 + 2*c0*c1*v^2). Algebraically identical to the tanh form.
    // NaN-free for finite v: e in [0,inf], v/(1+e) well-defined (0 at -inf).
    float v2 = v * v;
    float u2 = v * fmaf(v2, 0.07135481627260093f, 1.5957691216057308f);
    float e  = __expf(-u2);
    return v / (1.0f + e);
}

// ---------------- merged prepass ----------------
// Blocks [0, M_DIM/4): per-row dynamic int8 quantization of A (1 wave/row).
// Blocks [M_DIM/4, ...): pack int32 weights -> int8 (exact).
#define QA_BLOCKS (M_DIM / 4)
#define W4_COUNT  ((N_DIM * K_DIM) / 4)
#define PW_BLOCKS ((W4_COUNT + 255) / 256)

__global__ void prepass(const float* __restrict__ A,
                        const int* __restrict__ w,
                        signed char* __restrict__ qa,
                        float* __restrict__ sA,
                        signed char* __restrict__ qw) {
    if (blockIdx.x < QA_BLOCKS) {
        const int lane = threadIdx.x & 63;
        const int row  = blockIdx.x * 4 + (threadIdx.x >> 6);
        const float2* src = (const float2*)(A + (size_t)row * K_DIM);
        float2 v[9];
        float amax = 0.f;
#pragma unroll
        for (int j = 0; j < 9; ++j) {
            v[j] = src[j * 64 + lane];
            amax = fmaxf(amax, fmaxf(fabsf(v[j].x), fabsf(v[j].y)));
        }
#pragma unroll
        for (int off = 32; off > 0; off >>= 1)
            amax = fmaxf(amax, __shfl_xor(amax, off));
        amax = fmaxf(amax, 1e-30f);
        float inv = 127.0f / amax;
        if (lane == 0) sA[row] = amax * (1.0f / 127.0f);
        char2* dst = (char2*)(qa + (size_t)row * K_DIM);
#pragma unroll
        for (int j = 0; j < 9; ++j) {
            char2 o;
            o.x = (signed char)__float2int_rn(v[j].x * inv);
            o.y = (signed char)__float2int_rn(v[j].y * inv);
            dst[j * 64 + lane] = o;
        }
    } else {
        int i = (blockIdx.x - QA_BLOCKS) * 256 + threadIdx.x;
        if (i >= W4_COUNT) return;
        int4 v = ((const int4*)w)[i];
        char4 o;
        o.x = (signed char)v.x; o.y = (signed char)v.y;
        o.z = (signed char)v.z; o.w = (signed char)v.w;
        ((char4*)qw)[i] = o;
    }
}

// ---------------- i8 GEMM, 256x256 tile, 8-phase counted-vmcnt schedule ----
// 512 threads = 8 waves (2M x 4N), per-wave 128x64 output, BK=128 int8.
// K-loop identical to round 1 (verified correct). Epilogue stages gelu'd
// output through a per-wave XOR-swizzled LDS scratch and issues NT dwordx4
// stores with 256B row contiguity (full 128B lines). Handoff hardened after
// round-3 NaN: __syncthreads() drain at loop exit, scratch moved to buf1
// (idle since kt=NKT-2), and explicit lgkmcnt(0)+sched_barrier fences between
// the per-slab LDS write and read phases (raw s_barrier has no compiler drain
// semantics; hipcc may reorder LDS ops it thinks don't alias — rule 18/19).

template <int MH, int NH>
__device__ __forceinline__ void mfma_quad(v4i (&acc)[2][4][2][2],
                                          v4i (&a)[4][2],
                                          v4i (&b)[2][2][2]) {
    __builtin_amdgcn_s_setprio(1);
#pragma unroll
    for (int s = 0; s < 2; ++s)
#pragma unroll
        for (int mt = 0; mt < 4; ++mt)
#pragma unroll
            for (int nt = 0; nt < 2; ++nt)
                acc[MH][mt][NH][nt] = __builtin_amdgcn_mfma_i32_16x16x64_i8(
                    a[mt][s], b[NH][nt][s], acc[MH][mt][NH][nt], 0, 0, 0);
    __builtin_amdgcn_s_setprio(0);
}

__global__ __launch_bounds__(512, 2) void qgemm_i8_8phase(
    const signed char* __restrict__ Aq,
    const signed char* __restrict__ Wq,
    const float* __restrict__ sA,
    const float* __restrict__ w_scale,
    const float* __restrict__ bias,
    float* __restrict__ out) {
    // [buf][mat(A/B)][row*128 + slot*16 + byte]
    __shared__ __align__(16) signed char lds[2][2][256 * 128];

    const int tid    = threadIdx.x;
    const int l      = tid & 63;
    const int wv     = tid >> 6;       // 0..7
    const int lane16 = l & 15;
    const int quad   = l >> 4;

    // XCD-aware bijective swizzle: 1152 blocks = 8 XCDs x 144.
    const int bid = blockIdx.x;
    const int swz = (bid & 7) * (1152 / 8) + (bid >> 3);
    const int mt0 = (swz / 18) * 256;
    const int nt0 = (swz % 18) * 256;

    const int wm = (wv & 1) * 128;
    const int wn = (wv >> 1) * 64;

    auto stage_half = [&](int buf, int mat, int half, int kt) {
        const signed char* gbase =
            (mat == 0) ? (Aq + (size_t)mt0 * K_DIM) : (Wq + (size_t)nt0 * K_DIM);
#pragma unroll
        for (int j = 0; j < 2; ++j) {
            int q   = j * 512 + tid;            // 16B-chunk idx in half-tile
            int row = half * 128 + (q >> 3);    // tile row 0..255
            int c   = (q & 7) ^ (row & 7);      // pre-swizzled global chunk
            const signed char* g = gbase + (size_t)row * K_DIM + kt * 128 + c * 16;
            signed char* d = &lds[buf][mat][half * 16384 + (j * 512 + wv * 64) * 16];
            __builtin_amdgcn_global_load_lds(
                (const __attribute__((address_space(1))) unsigned int*)g,
                (__attribute__((address_space(3))) unsigned int*)d, 16, 0, 0);
        }
    };

    v4i acc[2][4][2][2];
#pragma unroll
    for (int mh = 0; mh < 2; ++mh)
#pragma unroll
        for (int mt = 0; mt < 4; ++mt)
#pragma unroll
            for (int nh = 0; nh < 2; ++nh)
#pragma unroll
                for (int nt = 0; nt < 2; ++nt)
                    acc[mh][mt][nh][nt] = v4i{0, 0, 0, 0};

    v4i a[4][2];      // current-mh A frags
    v4i b[2][2][2];   // both-nh B frags (live across the K-tile)

    auto ldA = [&](int cur, int mh, int mt, int s) -> v4i {
        int r = wm + mh * 64 + mt * 16 + lane16;
        int p = (s * 4 + quad) ^ (r & 7);
        return *(const v4i*)&lds[cur][0][r * 128 + p * 16];
    };
    auto ldB = [&](int cur, int nh, int nt, int s) -> v4i {
        int r = wn + nh * 32 + nt * 16 + lane16;
        int p = (s * 4 + quad) ^ (r & 7);
        return *(const v4i*)&lds[cur][1][r * 128 + p * 16];
    };

    // -------- prologue: kt0 fully + kt1 B-halves (12 loads/thread) --------
    stage_half(0, 0, 0, 0); stage_half(0, 0, 1, 0);
    stage_half(0, 1, 0, 0); stage_half(0, 1, 1, 0);
    stage_half(1, 1, 0, 1); stage_half(1, 1, 1, 1);
    asm volatile("s_waitcnt vmcnt(4)" ::: "memory");  // kt0 done, B(kt1) flying
    __builtin_amdgcn_sched_barrier(0);
    __builtin_amdgcn_s_barrier();

    for (int kt = 0; kt < NKT; ++kt) {
        const int cur = kt & 1, nxt = cur ^ 1;
        // ---- P1: quad (0,0) — 12 ds_reads; prefetch A0(kt+1)
#pragma unroll
        for (int mt = 0; mt < 4; ++mt)
#pragma unroll
            for (int s = 0; s < 2; ++s) a[mt][s] = ldA(cur, 0, mt, s);
#pragma unroll
        for (int nt = 0; nt < 2; ++nt)
#pragma unroll
            for (int s = 0; s < 2; ++s) b[0][nt][s] = ldB(cur, 0, nt, s);
        if (kt + 1 < NKT) stage_half(nxt, 0, 0, kt + 1);
        __builtin_amdgcn_s_barrier();
        mfma_quad<0, 0>(acc, a, b);
        __builtin_amdgcn_s_barrier();
        // ---- P2: quad (0,1) — 4 ds_reads; prefetch A1(kt+1)
#pragma unroll
        for (int nt = 0; nt < 2; ++nt)
#pragma unroll
            for (int s = 0; s < 2; ++s) b[1][nt][s] = ldB(cur, 1, nt, s);
        if (kt + 1 < NKT) stage_half(nxt, 0, 1, kt + 1);
        __builtin_amdgcn_s_barrier();
        mfma_quad<0, 1>(acc, a, b);
        __builtin_amdgcn_s_barrier();
        // ---- P3: quad (1,1) — 8 ds_reads; prefetch B0(kt+2) into cur
#pragma unroll
        for (int mt = 0; mt < 4; ++mt)
#pragma unroll
            for (int s = 0; s < 2; ++s) a[mt][s] = ldA(cur, 1, mt, s);
        if (kt + 2 < NKT) stage_half(cur, 1, 0, kt + 2);
        __builtin_amdgcn_s_barrier();
        mfma_quad<1, 1>(acc, a, b);
        __builtin_amdgcn_s_barrier();
        // ---- P4: quad (1,0) — 0 ds_reads; prefetch B1(kt+2); boundary wait
        if (kt + 2 < NKT) stage_half(cur, 1, 1, kt + 2);
        mfma_quad<1, 0>(acc, a, b);
        if (kt + 2 < NKT) {
            asm volatile("s_waitcnt vmcnt(4)" ::: "memory");  // kt+1 complete
        } else if (kt + 1 < NKT) {
            asm volatile("s_waitcnt vmcnt(0)" ::: "memory");  // tail drain
        }
        __builtin_amdgcn_sched_barrier(0);
        __builtin_amdgcn_s_barrier();
    }

    // ---- hard handoff: all waves' LDS ops drained before scratch reuse ----
    __syncthreads();

    // ---- epilogue: gelu -> per-wave LDS transpose -> 256B-contiguous NT ----
    // Per (mh,mt) round: wave stages 16 rows x 64 floats (4KB) with 16B-chunk
    // XOR swizzle (chunk ^= row16), reads back ds_read_b128, stores dwordx4:
    // 16 lanes x 16B = 256B contiguous per row. Scratch lives in buf1 (idle
    // since kt=NKT-2). Explicit fences order write->read->next-write.
    float sc[2][2], bi[2][2];
#pragma unroll
    for (int nh = 0; nh < 2; ++nh)
#pragma unroll
        for (int nt = 0; nt < 2; ++nt) {
            int n = nt0 + wn + nh * 32 + nt * 16 + lane16;
            sc[nh][nt] = w_scale[n];
            bi[nh][nt] = bias[n];
        }

    float* scr = (float*)(&lds[1][0][0]) + wv * 1024;  // 4KB per wave, buf1
    const int lo3 = lane16 & 3;

#pragma unroll
    for (int mh = 0; mh < 2; ++mh)
#pragma unroll
        for (int mt = 0; mt < 4; ++mt) {
            const int rbase = mt0 + wm + mh * 64 + mt * 16;  // global m of row16==0
            const f32x4 sa = *(const f32x4*)(sA + rbase + quad * 4);
#pragma unroll
            for (int nh = 0; nh < 2; ++nh)
#pragma unroll
                for (int nt = 0; nt < 2; ++nt) {
                    const int col   = nh * 32 + nt * 16 + lane16;  // 0..63
                    const int chunk = col >> 2;                    // 0..15
#pragma unroll
                    for (int r = 0; r < 4; ++r) {
                        const int row16 = quad * 4 + r;
                        const int c2    = chunk ^ row16;
                        float v = (float)acc[mh][mt][nh][nt][r] * sa[r] * sc[nh][nt] + bi[nh][nt];
                        scr[row16 * 64 + c2 * 4 + lo3] = gelu_tanh_f(v);
                    }
                }
            // writes complete (LDS data visible) before cross-lane readback
            asm volatile("s_waitcnt lgkmcnt(0)" ::: "memory");
            __builtin_amdgcn_sched_barrier(0);
#pragma unroll
            for (int s = 0; s < 4; ++s) {
                const int row16 = s * 4 + quad;
                const int c2    = lane16 ^ row16;   // logical chunk == lane16
                f32x4 val = *(const f32x4*)(scr + row16 * 64 + c2 * 4);
                __builtin_nontemporal_store(
                    val, (f32x4*)(out + (size_t)(rbase + row16) * N_DIM
                                  + nt0 + wn + lane16 * 4));
            }
            // reads land in VGPRs before next slab overwrites the scratch
            asm volatile("s_waitcnt lgkmcnt(0)" ::: "memory");
            __builtin_amdgcn_sched_barrier(0);
        }
}

// ---------------- bf16 fused fallback (if ws too small) --------------------
__global__ void qgelu_gemm_bf16_fused(const float* __restrict__ Af,
                                      const int* __restrict__ Wi,
                                      const float* __restrict__ w_scale,
                                      const float* __restrict__ bias,
                                      float* __restrict__ out) {
    __shared__ __align__(16) unsigned short As[128 * 64];
    __shared__ __align__(16) unsigned short Bs[128 * 64];

    const int tid    = threadIdx.x;
    const int l      = tid & 63;
    const int wv     = tid >> 6;
    const int lane16 = l & 15;
    const int quad   = l >> 4;
    const int m0 = blockIdx.x * 128;
    const int n0 = blockIdx.y * 128;
    const int wm = (wv & 1) * 64;
    const int wn = (wv >> 1) * 64;

    f32x4 acc[4][4];
#pragma unroll
    for (int i = 0; i < 4; ++i)
#pragma unroll
        for (int j = 0; j < 4; ++j) acc[i][j] = f32x4{0.f, 0.f, 0.f, 0.f};

    for (int kt = 0; kt < K_DIM / 64; ++kt) {
        __syncthreads();
#pragma unroll
        for (int i = 0; i < 8; ++i) {
            int g    = i * 256 + tid;
            int row  = g >> 4;
            int grp  = g & 15;
            int c    = grp >> 1;
            int half = g & 1;
            int p    = c ^ (row & 7);
            int off  = row * 64 + p * 8 + half * 4;
            {
                float4 v = *(const float4*)(Af + (size_t)(m0 + row) * K_DIM + kt * 64 + grp * 4);
                ushort4 o;
                o.x = f2bf(v.x); o.y = f2bf(v.y); o.z = f2bf(v.z); o.w = f2bf(v.w);
                *(ushort4*)(As + off) = o;
            }
            {
                int4 v = *(const int4*)(Wi + (size_t)(n0 + row) * K_DIM + kt * 64 + grp * 4);
                ushort4 o;
                o.x = f2bf((float)v.x); o.y = f2bf((float)v.y);
                o.z = f2bf((float)v.z); o.w = f2bf((float)v.w);
                *(ushort4*)(Bs + off) = o;
            }
        }
        __syncthreads();

#pragma unroll
        for (int s = 0; s < 2; ++s) {
            bf16x8 af[4], bfr[4];
#pragma unroll
            for (int mt = 0; mt < 4; ++mt) {
                int row = wm + mt * 16 + lane16;
                int p   = (s * 4 + quad) ^ (row & 7);
                af[mt]  = *(const bf16x8*)(As + row * 64 + p * 8);
            }
#pragma unroll
            for (int nt = 0; nt < 4; ++nt) {
                int row = wn + nt * 16 + lane16;
                int p   = (s * 4 + quad) ^ (row & 7);
                bfr[nt] = *(const bf16x8*)(Bs + row * 64 + p * 8);
            }
#pragma unroll
            for (int mt = 0; mt < 4; ++mt)
#pragma unroll
                for (int nt = 0; nt < 4; ++nt)
                    acc[mt][nt] = __builtin_amdgcn_mfma_f32_16x16x32_bf16(
                        af[mt], bfr[nt], acc[mt][nt], 0, 0, 0);
        }
    }

#pragma unroll
    for (int nt = 0; nt < 4; ++nt) {
        int n    = n0 + wn + nt * 16 + lane16;
        float sc = w_scale[n];
        float bi = bias[n];
#pragma unroll
        for (int mt = 0; mt < 4; ++mt) {
#pragma unroll
            for (int r = 0; r < 4; ++r) {
                int m   = m0 + wm + mt * 16 + quad * 4 + r;
                float v = acc[mt][nt][r] * sc + bi;
                __builtin_nontemporal_store(
                    gelu_tanh_f(v), &out[(size_t)m * N_DIM + n]);
            }
        }
    }
}

extern "C" void kernel_launch(void* const* d_in, const int* in_sizes, int n_in,
                              void* d_out, int out_size, void* d_ws, size_t ws_size,
                              hipStream_t stream) {
    const float* hs   = (const float*)d_in[0];  // [8,2048,1152] fp32
    const int*   w8   = (const int*)d_in[1];    // [4608,1152] int32 (int8 values)
    const float* wsc  = (const float*)d_in[2];  // [4608]
    const float* bias = (const float*)d_in[3];  // [4608]
    float* out = (float*)d_out;                 // [8,2048,4608] fp32

    const size_t nA = (size_t)M_DIM * K_DIM;  // int8 elems
    const size_t nW = (size_t)N_DIM * K_DIM;
    const size_t need = nA + nW + (size_t)M_DIM * sizeof(float);

    if (ws_size >= need) {
        signed char* qa = (signed char*)d_ws;
        signed char* qw = qa + nA;
        float* sA = (float*)(qa + nA + nW);  // 16B-aligned (nA+nW % 16 == 0)
        prepass<<<QA_BLOCKS + PW_BLOCKS, 256, 0, stream>>>(hs, w8, qa, sA, qw);
        qgemm_i8_8phase<<<dim3((M_DIM / 256) * (N_DIM / 256)), 512, 0, stream>>>(
            qa, qw, sA, wsc, bias, out);
    } else {
        dim3 grid(M_DIM / 128, N_DIM / 128);
        qgelu_gemm_bf16_fused<<<grid, 256, 0, stream>>>(hs, w8, wsc, bias, out);
    }
}